// Round 14
// baseline (181.053 us; speedup 1.0000x reference)
//
#include <hip/hip_runtime.h>
#include <hip/hip_fp16.h>
#include <math.h>

#define N_NODES 50000
#define N_EDGES 800000
#define F_IN    128
#define D_HID   96
#define NHEAD   8
#define DH      12
#define N_CLS   40
#define NEG_SLOPE 0.2f

#define NPART   (N_NODES / 8)        // 6250 dst nodes per XCD group
#define CKS     64                   // edge chunks
#define CHK     (N_EDGES / CKS)      // 12500 edges per chunk
#define NHB     (8 * CKS)            // 512 hist/fill blocks (group x chunk)

#define GBM 64                       // gemm rows per block
#define NGB ((N_NODES + GBM - 1) / GBM)   // 782
#define WPAD 136                     // LDS W row pad (272B: 16B aligned, 2-way banks = free)

#define HALFN   (N_NODES / 2)        // 25000
#define AGG_NPB 32                   // nodes per aggregate block (256 thr / 8 lanes)
#define NAGGB   ((HALFN + AGG_NPB - 1) / AGG_NPB)   // 782

#define NCH     196                  // 256-node degree-sort chunks (ceil(50000/256))

typedef _Float16 f16x8 __attribute__((ext_vector_type(8)));
typedef float    f32x4 __attribute__((ext_vector_type(4)));

// ---------------- MFMA GEMM core: H = A[M,K] @ W[K,96] (fp16 in, fp32 acc) ------------
// (r13 structure, unchanged) Epilogue packs PER-GROUP 64B RECORDS:
//   [aS_2q|h0..5][h6..11|aD_2q] [aS_2q+1|h12..17][h18..23|aD_2q+1]
template<bool A16>
__device__ __forceinline__ void gemm_alpha_mfma_body(
    const void* __restrict__ Av, const float* __restrict__ W,
    const float* __restrict__ asrc, const float* __restrict__ adst,
    uint4* __restrict__ Hrec,
    int M, int K, int bid,
    _Float16 (*Wt)[WPAD], _Float16 (*Hl)[104], float* avl, float* adl)
{
    int tid  = threadIdx.x;
    int lane = tid & 63;
    int w    = tid >> 6;
    int n0   = bid * GBM;

    for (int idx = tid; idx < K * 96; idx += 256) {
        int k = idx / 96, n = idx - k * 96;
        Wt[n][k] = (_Float16)W[idx];
    }
    if (tid < 96) { avl[tid] = asrc[tid]; adl[tid] = adst[tid]; }
    __syncthreads();

    int c  = lane & 15;
    int kg = lane >> 4;
    int arow = n0 + (w << 4) + c;
    int ar = arow < M ? arow : M - 1;

    f32x4 acc[6];
#pragma unroll
    for (int t = 0; t < 6; t++) acc[t] = (f32x4){0.f, 0.f, 0.f, 0.f};

    for (int k0 = 0; k0 < K; k0 += 32) {
        f16x8 av;
        if constexpr (A16) {
            const _Float16* ap = (const _Float16*)Av + (size_t)ar * K + (kg << 3);
            av = *(const f16x8*)(ap + k0);
        } else {
            const float* ap = (const float*)Av + (size_t)ar * K + (kg << 3);
            float4 a0 = *(const float4*)(ap + k0);
            float4 a1 = *(const float4*)(ap + k0 + 4);
            av[0] = (_Float16)a0.x; av[1] = (_Float16)a0.y;
            av[2] = (_Float16)a0.z; av[3] = (_Float16)a0.w;
            av[4] = (_Float16)a1.x; av[5] = (_Float16)a1.y;
            av[6] = (_Float16)a1.z; av[7] = (_Float16)a1.w;
        }
#pragma unroll
        for (int t = 0; t < 6; t++) {
            f16x8 bv = *(const f16x8*)&Wt[t * 16 + c][k0 + (kg << 3)];
            acc[t] = __builtin_amdgcn_mfma_f32_16x16x32_f16(av, bv, acc[t], 0, 0, 0);
        }
    }

    int rbase = (w << 4) + (kg << 2);
#pragma unroll
    for (int t = 0; t < 6; t++)
#pragma unroll
        for (int r = 0; r < 4; r++)
            Hl[rbase + r][t * 16 + c] = (_Float16)acc[t][r];
    __syncthreads();

    int row = tid >> 2, q = tid & 3;
    int gr = n0 + row;
    if (gr < M) {
        float s0 = 0.f, s1 = 0.f, d0 = 0.f, d1 = 0.f;
#pragma unroll
        for (int j = 0; j < 12; j++) {
            float f = (float)Hl[row][q * 24 + j];
            s0 += f * avl[q * 24 + j];
            d0 += f * adl[q * 24 + j];
        }
#pragma unroll
        for (int j = 12; j < 24; j++) {
            float f = (float)Hl[row][q * 24 + j];
            s1 += f * avl[q * 24 + j];
            d1 += f * adl[q * 24 + j];
        }
        const uint* hp = (const uint*)&Hl[row][q * 24];
        uint4* rec = Hrec + ((size_t)q * N_NODES + gr) * 4;
        rec[0] = make_uint4(__float_as_uint(s0), hp[0], hp[1], hp[2]);
        rec[1] = make_uint4(hp[3], hp[4], hp[5], __float_as_uint(d0));
        rec[2] = make_uint4(__float_as_uint(s1), hp[6], hp[7], hp[8]);
        rec[3] = make_uint4(hp[9], hp[10], hp[11], __float_as_uint(d1));
    }
}

// ------- fused: chunk-hist (blocks [0,NHB), NO global atomics) + gemm0 (rest) --------
__global__ __launch_bounds__(256) void hist_gemm_kernel(
    const int* __restrict__ edst, unsigned short* __restrict__ Hmat,
    const float* __restrict__ A, const float* __restrict__ W0,
    const float* __restrict__ asrc, const float* __restrict__ adst,
    uint4* __restrict__ Hrec)
{
    __shared__ __align__(16) char smem[40448];
    if (blockIdx.x < NHB) {
        int* lh = (int*)smem;                      // 25000 B
        int g = blockIdx.x & 7, c = blockIdx.x >> 3;
        int lo = g * NPART;
        for (int i = threadIdx.x; i < NPART; i += 256) lh[i] = 0;
        __syncthreads();
        const int4* d4 = (const int4*)(edst + c * CHK);
        for (int i = threadIdx.x; i < CHK / 4; i += 256) {
            int4 dv = d4[i];
            int a = dv.x - lo, b = dv.y - lo, cc = dv.z - lo, dd = dv.w - lo;
            if ((unsigned)a  < (unsigned)NPART) atomicAdd(&lh[a], 1);
            if ((unsigned)b  < (unsigned)NPART) atomicAdd(&lh[b], 1);
            if ((unsigned)cc < (unsigned)NPART) atomicAdd(&lh[cc], 1);
            if ((unsigned)dd < (unsigned)NPART) atomicAdd(&lh[dd], 1);
        }
        __syncthreads();
        unsigned int* hrow = (unsigned int*)(Hmat + (size_t)c * N_NODES + lo);
        for (int i = threadIdx.x; i < NPART / 2; i += 256)
            hrow[i] = (unsigned)lh[2 * i] | ((unsigned)lh[2 * i + 1] << 16);
    } else {
        _Float16 (*Wt)[WPAD] = (_Float16(*)[WPAD])smem;
        _Float16 (*Hl)[104]  = (_Float16(*)[104])(smem + 26112);
        float* avl = (float*)(smem + 26112 + 13312);
        float* adl = avl + 96;
        gemm_alpha_mfma_body<false>(A, W0, asrc, adst, Hrec, N_NODES, F_IN,
                                    blockIdx.x - NHB, Wt, Hl, avl, adl);
    }
}

// ---------------- standalone gemm (layer 1, fp16 A, K=96) ----------------
__global__ __launch_bounds__(256) void gemm_alpha_kernel(
    const _Float16* __restrict__ A, const float* __restrict__ W1,
    const float* __restrict__ asrc, const float* __restrict__ adst,
    uint4* __restrict__ Hrec, int M, int K)
{
    __shared__ __align__(16) char smem[40448];
    _Float16 (*Wt)[WPAD] = (_Float16(*)[WPAD])smem;
    _Float16 (*Hl)[104]  = (_Float16(*)[104])(smem + 26112);
    float* avl = (float*)(smem + 26112 + 13312);
    float* adl = avl + 96;
    gemm_alpha_mfma_body<true>(A, W1, asrc, adst, Hrec, M, K, blockIdx.x,
                               Wt, Hl, avl, adl);
}

// ---------------- scans (no global atomics anywhere) ----------------
// scan1: per-bin chunk-sum + block-inclusive scan + DEGREE HISTOGRAM per 256-node
// sub-chunk (for the counting sort). Dhist[(bid*4+sc)*256 + bin], all entries written.
__global__ void scan1_kernel(const unsigned short* __restrict__ Hmat,
                             int* __restrict__ incl,
                             int* __restrict__ partials,
                             int* __restrict__ Dhist, int n) {
    __shared__ int sdata[256];
    __shared__ int dh[4 * 256];
    int t = threadIdx.x;
    for (int k = t; k < 1024; k += 256) dh[k] = 0;
    __syncthreads();
    int base = blockIdx.x * 1024 + t * 4;
    int v[4] = {0, 0, 0, 0};
    if (base + 4 <= n) {
        for (int c = 0; c < CKS; c++) {
            ushort4 h = *(const ushort4*)&Hmat[(size_t)c * N_NODES + base];
            v[0] += h.x; v[1] += h.y; v[2] += h.z; v[3] += h.w;
        }
    } else if (base < n) {
        for (int c = 0; c < CKS; c++)
#pragma unroll
            for (int j = 0; j < 4; j++)
                if (base + j < n) v[j] += Hmat[(size_t)c * N_NODES + base + j];
    }
    // degree histogram (before inclusive transform)
    int sc = t >> 6;
#pragma unroll
    for (int j = 0; j < 4; j++)
        if (base + j < n) atomicAdd(&dh[sc * 256 + (v[j] > 255 ? 255 : v[j])], 1);
    v[1] += v[0]; v[2] += v[1]; v[3] += v[2];
    sdata[t] = v[3];
    __syncthreads();
    for (int off = 1; off < 256; off <<= 1) {
        int x = (t >= off) ? sdata[t - off] : 0;
        __syncthreads();
        sdata[t] += x;
        __syncthreads();
    }
    int excl = sdata[t] - v[3];
#pragma unroll
    for (int j = 0; j < 4; j++) { int i = base + j; if (i < n) incl[i] = v[j] + excl; }
    if (t == 255) partials[blockIdx.x] = sdata[255];
    for (int k = t; k < 1024; k += 256)
        Dhist[blockIdx.x * 1024 + k] = dh[k];
}

// dbase: per-(chunk,bin) start positions for the counting sort. 1 block.
__global__ void dbase_kernel(const int* __restrict__ Dhist, int* __restrict__ dbase) {
    __shared__ int sdata[256];
    int b = threadIdx.x;
    int tot = 0;
    for (int c = 0; c < NCH; c++) tot += Dhist[c * 256 + b];
    sdata[b] = tot;
    __syncthreads();
    for (int off = 1; off < 256; off <<= 1) {
        int x = (b >= off) ? sdata[b - off] : 0;
        __syncthreads();
        sdata[b] += x;
        __syncthreads();
    }
    int run = sdata[b] - tot;          // exclusive bin start
    for (int c = 0; c < NCH; c++) {
        dbase[c * 256 + b] = run;
        run += Dhist[c * 256 + b];
    }
}

// scan3: rowptr + uint16 relative chunk offsets + counting-sort placement (LDS cursor).
__global__ void scan3_kernel(const int* __restrict__ incl,
                             const int* __restrict__ partials,
                             const unsigned short* __restrict__ Hmat,
                             const int* __restrict__ dbase,
                             unsigned short* __restrict__ Bmat16,
                             int* __restrict__ rowptr,
                             unsigned short* __restrict__ perm,
                             int n, int nb) {
    __shared__ int cur[256];
    int t = threadIdx.x;
    cur[t] = dbase[blockIdx.x * 256 + t];
    __syncthreads();
    int i = blockIdx.x * blockDim.x + t;
    if (i >= n) return;
    int myb = i >> 10;
    int psum = 0;
    for (int b = 0; b < nb; b++) psum += (b < myb) ? partials[b] : 0;
    int iv = incl[i];
    int v = iv + psum;
    rowptr[i + 1] = v;
    if (i == 0) rowptr[0] = 0;
    int deg = ((i & 1023) == 0) ? iv : iv - incl[i - 1];
    int running = 0;
    for (int c = 0; c < CKS; c++) {
        Bmat16[(size_t)c * N_NODES + i] = (unsigned short)running;
        running += Hmat[(size_t)c * N_NODES + i];
    }
    int pos = atomicAdd(&cur[deg > 255 ? 255 : deg], 1);
    perm[pos] = (unsigned short)i;
}

// fill: LDS cursor = rowptr + rel offset; LDS atomics only; scattered srclist stores.
__global__ __launch_bounds__(256) void fill_kernel(
    const int* __restrict__ esrc, const int* __restrict__ edst,
    const int* __restrict__ rowptr, const unsigned short* __restrict__ Bmat16,
    unsigned short* __restrict__ srclist)
{
    __shared__ int cur[NPART];
    int g = blockIdx.x & 7, c = blockIdx.x >> 3;
    int lo = g * NPART;
    const unsigned short* rrow = Bmat16 + (size_t)c * N_NODES + lo;
    const int* rp = rowptr + lo;
    for (int i = threadIdx.x; i < NPART; i += 256) cur[i] = rp[i] + rrow[i];
    __syncthreads();
    int base = c * CHK;
    const int4* d4 = (const int4*)(edst + base);
    const int4* s4 = (const int4*)(esrc + base);
    for (int i = threadIdx.x; i < CHK / 4; i += 256) {
        int4 dv = d4[i], sv = s4[i];
        int a = dv.x - lo, b = dv.y - lo, cc = dv.z - lo, dd = dv.w - lo;
        if ((unsigned)a < (unsigned)NPART) {
            int p = atomicAdd(&cur[a], 1); srclist[p] = (unsigned short)sv.x;
        }
        if ((unsigned)b < (unsigned)NPART) {
            int p = atomicAdd(&cur[b], 1); srclist[p] = (unsigned short)sv.y;
        }
        if ((unsigned)cc < (unsigned)NPART) {
            int p = atomicAdd(&cur[cc], 1); srclist[p] = (unsigned short)sv.z;
        }
        if ((unsigned)dd < (unsigned)NPART) {
            int p = atomicAdd(&cur[dd], 1); srclist[p] = (unsigned short)sv.w;
        }
    }
}

// ---------------- GAT aggregation: packed records, XCD-partitioned, DEGREE-SORTED ----
// Nodes taken through perm (degree-ascending): a wave's 8 nodes have ~equal degrees,
// eliminating the max-of-8 Poisson imbalance (~60% of wave time unsorted).
__device__ __forceinline__ void agg_rec(const uint4* __restrict__ rp, float ad,
                                        float& z, float* acc) {
    uint4 u0 = rp[0], u1 = rp[1];
    float e = __uint_as_float(u0.x) + ad;
    e = (e > 0.f) ? e : NEG_SLOPE * e;
    float p = __expf(e);
    z += p;
    float2 f0 = __half22float2(*(const __half2*)&u0.y);
    float2 f1 = __half22float2(*(const __half2*)&u0.z);
    float2 f2 = __half22float2(*(const __half2*)&u0.w);
    float2 f3 = __half22float2(*(const __half2*)&u1.x);
    float2 f4 = __half22float2(*(const __half2*)&u1.y);
    float2 f5 = __half22float2(*(const __half2*)&u1.z);
    acc[0] += p * f0.x; acc[1]  += p * f0.y;
    acc[2] += p * f1.x; acc[3]  += p * f1.y;
    acc[4] += p * f2.x; acc[5]  += p * f2.y;
    acc[6] += p * f3.x; acc[7]  += p * f3.y;
    acc[8] += p * f4.x; acc[9]  += p * f4.y;
    acc[10] += p * f5.x; acc[11] += p * f5.y;
}

__global__ __launch_bounds__(256) void gat_aggregate_kernel(
    const uint4* __restrict__ Hrec,
    const int* __restrict__ rowptr, const unsigned short* __restrict__ srclist,
    const unsigned short* __restrict__ perm,
    const float* __restrict__ bias,
    _Float16* __restrict__ outYh, float* __restrict__ outY, int mode)
{
    int s    = blockIdx.x & 7;
    int g    = s >> 1;
    int half = s & 1;
    int p_s  = (blockIdx.x >> 3) * AGG_NPB + (threadIdx.x >> 3);
    if (p_s >= HALFN) return;
    int n   = perm[p_s * 2 + half];      // degree-sorted node
    int l   = threadIdx.x & 7;
    int hh2 = l & 1;
    int j   = l >> 1;

    const uint4* gtab = Hrec + (size_t)g * N_NODES * 4;
    float ad = __uint_as_float(gtab[(size_t)n * 4 + hh2 * 2 + 1].w);

    int s0 = rowptr[n], s1 = rowptr[n + 1];
    float z = 0.f;
    float acc[12];
#pragma unroll
    for (int t = 0; t < 12; t++) acc[t] = 0.f;

    int i = s0 + j;
    for (; i + 12 < s1; i += 16) {
        int sa = srclist[i];
        int sb = srclist[i + 4];
        int sc = srclist[i + 8];
        int sd = srclist[i + 12];
        agg_rec(gtab + (size_t)sa * 4 + hh2 * 2, ad, z, acc);
        agg_rec(gtab + (size_t)sb * 4 + hh2 * 2, ad, z, acc);
        agg_rec(gtab + (size_t)sc * 4 + hh2 * 2, ad, z, acc);
        agg_rec(gtab + (size_t)sd * 4 + hh2 * 2, ad, z, acc);
    }
    for (; i < s1; i += 4) {
        int sa = srclist[i];
        agg_rec(gtab + (size_t)sa * 4 + hh2 * 2, ad, z, acc);
    }

#pragma unroll
    for (int m = 2; m <= 4; m <<= 1) {
        z += __shfl_xor(z, m, 64);
#pragma unroll
        for (int t = 0; t < 12; t++) acc[t] += __shfl_xor(acc[t], m, 64);
    }

    if (j == 0) {
        float inv = 1.f / (z + 1e-16f);
        const float* bp = bias + g * 24 + hh2 * 12;
        float o[12];
#pragma unroll
        for (int t = 0; t < 12; t++) o[t] = acc[t] * inv + bp[t];
        if (mode == 0) {
            uint ww[6];
#pragma unroll
            for (int t = 0; t < 6; t++) {
                __half2 hv = __floats2half2_rn(o[2 * t], o[2 * t + 1]);
                ww[t] = *(const uint*)&hv;
            }
            uint2* yp = (uint2*)(outYh + (size_t)n * D_HID + g * 24 + hh2 * 12);
            yp[0] = make_uint2(ww[0], ww[1]);
            yp[1] = make_uint2(ww[2], ww[3]);
            yp[2] = make_uint2(ww[4], ww[5]);
        } else {
#pragma unroll
            for (int t = 0; t < 12; t++) o[t] = fmaxf(o[t], 0.f);
            float4* op = (float4*)(outY + (size_t)n * D_HID + g * 24 + hh2 * 12);
            op[0] = make_float4(o[0], o[1], o[2], o[3]);
            op[1] = make_float4(o[4], o[5], o[6], o[7]);
            op[2] = make_float4(o[8], o[9], o[10], o[11]);
        }
    }
}

// ---------------- final linear (96->40) + bias + log_softmax, thread per node --------
__global__ __launch_bounds__(256) void out_lsm_kernel(
    const float* __restrict__ X, const float* __restrict__ Wout,
    const float* __restrict__ bout, float* __restrict__ out)
{
    __shared__ float Ws[D_HID * N_CLS];
    __shared__ float bs[N_CLS];
    for (int i = threadIdx.x; i < D_HID * N_CLS; i += 256) Ws[i] = Wout[i];
    for (int i = threadIdx.x; i < N_CLS; i += 256) bs[i] = bout[i];
    __syncthreads();

    int n = blockIdx.x * blockDim.x + threadIdx.x;
    if (n >= N_NODES) return;

    float acc[N_CLS];
#pragma unroll
    for (int c = 0; c < N_CLS; c++) acc[c] = bs[c];

    const float4* xp = (const float4*)(X + (size_t)n * D_HID);
    for (int k4 = 0; k4 < D_HID / 4; k4++) {
        float4 xv = xp[k4];
        const float* wrow = &Ws[(k4 * 4) * N_CLS];
#pragma unroll
        for (int c4 = 0; c4 < N_CLS / 4; c4++) {
            float4 wa = *(const float4*)(wrow + c4 * 4);
            float4 wb = *(const float4*)(wrow + N_CLS + c4 * 4);
            float4 wc = *(const float4*)(wrow + 2 * N_CLS + c4 * 4);
            float4 wd = *(const float4*)(wrow + 3 * N_CLS + c4 * 4);
            acc[c4 * 4 + 0] += xv.x * wa.x + xv.y * wb.x + xv.z * wc.x + xv.w * wd.x;
            acc[c4 * 4 + 1] += xv.x * wa.y + xv.y * wb.y + xv.z * wc.y + xv.w * wd.y;
            acc[c4 * 4 + 2] += xv.x * wa.z + xv.y * wb.z + xv.z * wc.z + xv.w * wd.z;
            acc[c4 * 4 + 3] += xv.x * wa.w + xv.y * wb.w + xv.z * wc.w + xv.w * wd.w;
        }
    }

    float m = acc[0];
#pragma unroll
    for (int c = 1; c < N_CLS; c++) m = fmaxf(m, acc[c]);
    float s = 0.f;
#pragma unroll
    for (int c = 0; c < N_CLS; c++) s += __expf(acc[c] - m);
    float lg = __logf(s);

    float4* op = (float4*)(out + (size_t)n * N_CLS);
#pragma unroll
    for (int c4 = 0; c4 < N_CLS / 4; c4++) {
        op[c4] = make_float4(acc[c4 * 4 + 0] - m - lg, acc[c4 * 4 + 1] - m - lg,
                             acc[c4 * 4 + 2] - m - lg, acc[c4 * 4 + 3] - m - lg);
    }
}

extern "C" void kernel_launch(void* const* d_in, const int* in_sizes, int n_in,
                              void* d_out, int out_size, void* d_ws, size_t ws_size,
                              hipStream_t stream)
{
    const float* x    = (const float*)d_in[0];
    const int*   esrc = (const int*)d_in[1];
    const int*   edst = (const int*)d_in[2];
    const float* W0   = (const float*)d_in[3];
    const float* as0  = (const float*)d_in[4];
    const float* ad0  = (const float*)d_in[5];
    const float* b0   = (const float*)d_in[6];
    const float* W1   = (const float*)d_in[7];
    const float* as1  = (const float*)d_in[8];
    const float* ad1  = (const float*)d_in[9];
    const float* b1   = (const float*)d_in[10];
    const float* Wout = (const float*)d_in[11];
    const float* bout = (const float*)d_in[12];
    float* out = (float*)d_out;

    char* p = (char*)d_ws;
    float*    bufY  = (float*)p;    p += (size_t)N_NODES * D_HID * sizeof(float);
    _Float16* bufYh = (_Float16*)p; p += (size_t)N_NODES * D_HID * sizeof(_Float16);
    uint4*    Hrec  = (uint4*)p;    p += (size_t)4 * N_NODES * 64;   // 4 groups x 64B records
    int*   rowptr = (int*)p;   p += ((size_t)N_NODES + 16) * sizeof(int);
    int*   incl   = (int*)p;   p += ((size_t)N_NODES + 16) * sizeof(int);
    unsigned short* srclist = (unsigned short*)p; p += (size_t)N_EDGES * sizeof(unsigned short);
    int*   partials = (int*)p; p += 256;
    int*   Dhist  = (int*)p;   p += (size_t)NCH * 256 * sizeof(int);
    int*   dbase  = (int*)p;   p += (size_t)NCH * 256 * sizeof(int);
    unsigned short* perm = (unsigned short*)p; p += (size_t)N_NODES * sizeof(unsigned short);

    // aliases with disjoint lifetimes (CSR build phase vs layer outputs):
    unsigned short* Hmat   = (unsigned short*)bufYh;   // dead before agg0 writes bufYh
    unsigned short* Bmat16 = (unsigned short*)bufY;    // dead before agg1 writes bufY

    int nscan = (N_NODES + 1023) / 1024;   // 49

    // 1. chunk-hist (LDS atomics only) + MFMA gemm0 (records out)
    hist_gemm_kernel<<<NHB + NGB, 256, 0, stream>>>(
        edst, Hmat, x, W0, as0, ad0, Hrec);
    // 2. per-bin chunk-sum + block scan + degree histograms
    scan1_kernel<<<nscan, 256, 0, stream>>>(Hmat, incl, partials, Dhist, N_NODES);
    // 3. counting-sort bases (1 block, tiny)
    dbase_kernel<<<1, 256, 0, stream>>>(Dhist, dbase);
    // 4. rowptr + relative chunk offsets + sorted placement
    scan3_kernel<<<(N_NODES + 255) / 256, 256, 0, stream>>>(
        incl, partials, Hmat, dbase, Bmat16, rowptr, perm, N_NODES, nscan);
    // 5. fill CSR (LDS cursor, no global atomics)
    fill_kernel<<<NHB, 256, 0, stream>>>(esrc, edst, rowptr, Bmat16, srclist);
    // 6. layer-0 aggregate (degree-sorted, XCD-partitioned) -> fp16 y
    gat_aggregate_kernel<<<8 * NAGGB, 256, 0, stream>>>(
        Hrec, rowptr, srclist, perm, b0, bufYh, bufY, 0);
    // 7. layer-1 MFMA gemm (fp16 A) -> records
    gemm_alpha_kernel<<<NGB, 256, 0, stream>>>(
        bufYh, W1, as1, ad1, Hrec, N_NODES, D_HID);
    // 8. layer-1 aggregate + relu (degree-sorted) -> fp32 y
    gat_aggregate_kernel<<<8 * NAGGB, 256, 0, stream>>>(
        Hrec, rowptr, srclist, perm, b1, bufYh, bufY, 1);
    // 9. output linear + log_softmax
    out_lsm_kernel<<<(N_NODES + 255) / 256, 256, 0, stream>>>(bufY, Wout, bout, out);
}

// Round 15
// 160.819 us; speedup vs baseline: 1.1258x; 1.1258x over previous
//
#include <hip/hip_runtime.h>
#include <hip/hip_fp16.h>
#include <math.h>

#define N_NODES 50000
#define N_EDGES 800000
#define F_IN    128
#define D_HID   96
#define NHEAD   8
#define DH      12
#define N_CLS   40
#define NEG_SLOPE 0.2f

#define NPART   (N_NODES / 8)        // 6250 dst nodes per XCD group
#define CKS     64                   // edge chunks
#define CHK     (N_EDGES / CKS)      // 12500 edges per chunk
#define NHB     (8 * CKS)            // 512 hist/fill blocks (group x chunk)

#define GBM 64                       // gemm rows per block
#define NGB ((N_NODES + GBM - 1) / GBM)   // 782
#define WPAD 136                     // LDS W row pad (272B: 16B aligned, 2-way banks = free)

#define HALFN   (N_NODES / 2)        // 25000
#define AGG_NPB 32                   // nodes per aggregate block (256 thr / 8 lanes)
#define NAGGB   ((HALFN + AGG_NPB - 1) / AGG_NPB)   // 782

typedef _Float16 f16x8 __attribute__((ext_vector_type(8)));
typedef float    f32x4 __attribute__((ext_vector_type(4)));

// ---------------- MFMA GEMM core: H = A[M,K] @ W[K,96] (fp16 in, fp32 acc) ------------
// (r12/r13-proven structure) Epilogue packs PER-GROUP 64B RECORDS:
//   [aS_2q|h0..5][h6..11|aD_2q] [aS_2q+1|h12..17][h18..23|aD_2q+1]
template<bool A16>
__device__ __forceinline__ void gemm_alpha_mfma_body(
    const void* __restrict__ Av, const float* __restrict__ W,
    const float* __restrict__ asrc, const float* __restrict__ adst,
    uint4* __restrict__ Hrec,
    int M, int K, int bid,
    _Float16 (*Wt)[WPAD], _Float16 (*Hl)[104], float* avl, float* adl)
{
    int tid  = threadIdx.x;
    int lane = tid & 63;
    int w    = tid >> 6;
    int n0   = bid * GBM;

    for (int idx = tid; idx < K * 96; idx += 256) {
        int k = idx / 96, n = idx - k * 96;
        Wt[n][k] = (_Float16)W[idx];
    }
    if (tid < 96) { avl[tid] = asrc[tid]; adl[tid] = adst[tid]; }
    __syncthreads();

    int c  = lane & 15;
    int kg = lane >> 4;
    int arow = n0 + (w << 4) + c;
    int ar = arow < M ? arow : M - 1;

    f32x4 acc[6];
#pragma unroll
    for (int t = 0; t < 6; t++) acc[t] = (f32x4){0.f, 0.f, 0.f, 0.f};

    for (int k0 = 0; k0 < K; k0 += 32) {
        f16x8 av;
        if constexpr (A16) {
            const _Float16* ap = (const _Float16*)Av + (size_t)ar * K + (kg << 3);
            av = *(const f16x8*)(ap + k0);
        } else {
            const float* ap = (const float*)Av + (size_t)ar * K + (kg << 3);
            float4 a0 = *(const float4*)(ap + k0);
            float4 a1 = *(const float4*)(ap + k0 + 4);
            av[0] = (_Float16)a0.x; av[1] = (_Float16)a0.y;
            av[2] = (_Float16)a0.z; av[3] = (_Float16)a0.w;
            av[4] = (_Float16)a1.x; av[5] = (_Float16)a1.y;
            av[6] = (_Float16)a1.z; av[7] = (_Float16)a1.w;
        }
#pragma unroll
        for (int t = 0; t < 6; t++) {
            f16x8 bv = *(const f16x8*)&Wt[t * 16 + c][k0 + (kg << 3)];
            acc[t] = __builtin_amdgcn_mfma_f32_16x16x32_f16(av, bv, acc[t], 0, 0, 0);
        }
    }

    int rbase = (w << 4) + (kg << 2);
#pragma unroll
    for (int t = 0; t < 6; t++)
#pragma unroll
        for (int r = 0; r < 4; r++)
            Hl[rbase + r][t * 16 + c] = (_Float16)acc[t][r];
    __syncthreads();

    int row = tid >> 2, q = tid & 3;
    int gr = n0 + row;
    if (gr < M) {
        float s0 = 0.f, s1 = 0.f, d0 = 0.f, d1 = 0.f;
#pragma unroll
        for (int j = 0; j < 12; j++) {
            float f = (float)Hl[row][q * 24 + j];
            s0 += f * avl[q * 24 + j];
            d0 += f * adl[q * 24 + j];
        }
#pragma unroll
        for (int j = 12; j < 24; j++) {
            float f = (float)Hl[row][q * 24 + j];
            s1 += f * avl[q * 24 + j];
            d1 += f * adl[q * 24 + j];
        }
        const uint* hp = (const uint*)&Hl[row][q * 24];
        uint4* rec = Hrec + ((size_t)q * N_NODES + gr) * 4;
        rec[0] = make_uint4(__float_as_uint(s0), hp[0], hp[1], hp[2]);
        rec[1] = make_uint4(hp[3], hp[4], hp[5], __float_as_uint(d0));
        rec[2] = make_uint4(__float_as_uint(s1), hp[6], hp[7], hp[8]);
        rec[3] = make_uint4(hp[9], hp[10], hp[11], __float_as_uint(d1));
    }
}

// ------- fused: chunk-hist (blocks [0,NHB), NO global atomics) + gemm0 (rest) --------
__global__ __launch_bounds__(256) void hist_gemm_kernel(
    const int* __restrict__ edst, unsigned short* __restrict__ Hmat,
    const float* __restrict__ A, const float* __restrict__ W0,
    const float* __restrict__ asrc, const float* __restrict__ adst,
    uint4* __restrict__ Hrec)
{
    __shared__ __align__(16) char smem[40448];
    if (blockIdx.x < NHB) {
        int* lh = (int*)smem;                      // 25000 B
        int g = blockIdx.x & 7, c = blockIdx.x >> 3;
        int lo = g * NPART;
        for (int i = threadIdx.x; i < NPART; i += 256) lh[i] = 0;
        __syncthreads();
        const int4* d4 = (const int4*)(edst + c * CHK);
        for (int i = threadIdx.x; i < CHK / 4; i += 256) {
            int4 dv = d4[i];
            int a = dv.x - lo, b = dv.y - lo, cc = dv.z - lo, dd = dv.w - lo;
            if ((unsigned)a  < (unsigned)NPART) atomicAdd(&lh[a], 1);
            if ((unsigned)b  < (unsigned)NPART) atomicAdd(&lh[b], 1);
            if ((unsigned)cc < (unsigned)NPART) atomicAdd(&lh[cc], 1);
            if ((unsigned)dd < (unsigned)NPART) atomicAdd(&lh[dd], 1);
        }
        __syncthreads();
        unsigned int* hrow = (unsigned int*)(Hmat + (size_t)c * N_NODES + lo);
        for (int i = threadIdx.x; i < NPART / 2; i += 256)
            hrow[i] = (unsigned)lh[2 * i] | ((unsigned)lh[2 * i + 1] << 16);
    } else {
        _Float16 (*Wt)[WPAD] = (_Float16(*)[WPAD])smem;
        _Float16 (*Hl)[104]  = (_Float16(*)[104])(smem + 26112);
        float* avl = (float*)(smem + 26112 + 13312);
        float* adl = avl + 96;
        gemm_alpha_mfma_body<false>(A, W0, asrc, adst, Hrec, N_NODES, F_IN,
                                    blockIdx.x - NHB, Wt, Hl, avl, adl);
    }
}

// ---------------- standalone gemm (layer 1, fp16 A, K=96) ----------------
__global__ __launch_bounds__(256) void gemm_alpha_kernel(
    const _Float16* __restrict__ A, const float* __restrict__ W1,
    const float* __restrict__ asrc, const float* __restrict__ adst,
    uint4* __restrict__ Hrec, int M, int K)
{
    __shared__ __align__(16) char smem[40448];
    _Float16 (*Wt)[WPAD] = (_Float16(*)[WPAD])smem;
    _Float16 (*Hl)[104]  = (_Float16(*)[104])(smem + 26112);
    float* avl = (float*)(smem + 26112 + 13312);
    float* adl = avl + 96;
    gemm_alpha_mfma_body<true>(A, W1, asrc, adst, Hrec, M, K, blockIdx.x,
                               Wt, Hl, avl, adl);
}

// ---------------- scans (no atomics anywhere) ----------------
__global__ void scan1_kernel(const unsigned short* __restrict__ Hmat,
                             int* __restrict__ incl,
                             int* __restrict__ partials, int n) {
    __shared__ int sdata[256];
    int t = threadIdx.x;
    int base = blockIdx.x * 1024 + t * 4;
    int v[4] = {0, 0, 0, 0};
    if (base + 4 <= n) {
        for (int c = 0; c < CKS; c++) {
            ushort4 h = *(const ushort4*)&Hmat[(size_t)c * N_NODES + base];
            v[0] += h.x; v[1] += h.y; v[2] += h.z; v[3] += h.w;
        }
    } else if (base < n) {
        for (int c = 0; c < CKS; c++)
#pragma unroll
            for (int j = 0; j < 4; j++)
                if (base + j < n) v[j] += Hmat[(size_t)c * N_NODES + base + j];
    }
    v[1] += v[0]; v[2] += v[1]; v[3] += v[2];
    sdata[t] = v[3];
    __syncthreads();
    for (int off = 1; off < 256; off <<= 1) {
        int x = (t >= off) ? sdata[t - off] : 0;
        __syncthreads();
        sdata[t] += x;
        __syncthreads();
    }
    int excl = sdata[t] - v[3];
#pragma unroll
    for (int j = 0; j < 4; j++) { int i = base + j; if (i < n) incl[i] = v[j] + excl; }
    if (t == 255) partials[blockIdx.x] = sdata[255];
}

// scan3: rowptr + per-(chunk,bin) RELATIVE base offsets (uint16: max = degree << 64K).
__global__ void scan3_kernel(const int* __restrict__ incl,
                             const int* __restrict__ partials,
                             const unsigned short* __restrict__ Hmat,
                             unsigned short* __restrict__ Bmat16,
                             int* __restrict__ rowptr,
                             int n, int nb) {
    int i = blockIdx.x * blockDim.x + threadIdx.x;
    if (i >= n) return;
    int myb = i >> 10;
    int psum = 0;
    for (int b = 0; b < nb; b++) psum += (b < myb) ? partials[b] : 0;
    int v = incl[i] + psum;
    rowptr[i + 1] = v;
    if (i == 0) rowptr[0] = 0;
    int running = 0;
    for (int c = 0; c < CKS; c++) {
        Bmat16[(size_t)c * N_NODES + i] = (unsigned short)running;
        running += Hmat[(size_t)c * N_NODES + i];
    }
}

// fill: LDS cursor = rowptr + rel offset; LDS atomics only; scattered srclist stores.
__global__ __launch_bounds__(256) void fill_kernel(
    const int* __restrict__ esrc, const int* __restrict__ edst,
    const int* __restrict__ rowptr, const unsigned short* __restrict__ Bmat16,
    unsigned short* __restrict__ srclist)
{
    __shared__ int cur[NPART];
    int g = blockIdx.x & 7, c = blockIdx.x >> 3;
    int lo = g * NPART;
    const unsigned short* rrow = Bmat16 + (size_t)c * N_NODES + lo;
    const int* rp = rowptr + lo;
    for (int i = threadIdx.x; i < NPART; i += 256) cur[i] = rp[i] + rrow[i];
    __syncthreads();
    int base = c * CHK;
    const int4* d4 = (const int4*)(edst + base);
    const int4* s4 = (const int4*)(esrc + base);
    for (int i = threadIdx.x; i < CHK / 4; i += 256) {
        int4 dv = d4[i], sv = s4[i];
        int a = dv.x - lo, b = dv.y - lo, cc = dv.z - lo, dd = dv.w - lo;
        if ((unsigned)a < (unsigned)NPART) {
            int p = atomicAdd(&cur[a], 1); srclist[p] = (unsigned short)sv.x;
        }
        if ((unsigned)b < (unsigned)NPART) {
            int p = atomicAdd(&cur[b], 1); srclist[p] = (unsigned short)sv.y;
        }
        if ((unsigned)cc < (unsigned)NPART) {
            int p = atomicAdd(&cur[cc], 1); srclist[p] = (unsigned short)sv.z;
        }
        if ((unsigned)dd < (unsigned)NPART) {
            int p = atomicAdd(&cur[dd], 1); srclist[p] = (unsigned short)sv.w;
        }
    }
}

// ---------------- GAT aggregation: packed records, XCD-partitioned (r12-proven) ------
// Both layers write fp16 y (mode selects relu). fp16 y is precision-neutral for
// layer 0 (gemm1 rounds A to fp16 anyway) and adds ~1e-3 rel error to layer-1 logits.
__device__ __forceinline__ void agg_rec(const uint4* __restrict__ rp, float ad,
                                        float& z, float* acc) {
    uint4 u0 = rp[0], u1 = rp[1];
    float e = __uint_as_float(u0.x) + ad;
    e = (e > 0.f) ? e : NEG_SLOPE * e;
    float p = __expf(e);
    z += p;
    float2 f0 = __half22float2(*(const __half2*)&u0.y);
    float2 f1 = __half22float2(*(const __half2*)&u0.z);
    float2 f2 = __half22float2(*(const __half2*)&u0.w);
    float2 f3 = __half22float2(*(const __half2*)&u1.x);
    float2 f4 = __half22float2(*(const __half2*)&u1.y);
    float2 f5 = __half22float2(*(const __half2*)&u1.z);
    acc[0] += p * f0.x; acc[1]  += p * f0.y;
    acc[2] += p * f1.x; acc[3]  += p * f1.y;
    acc[4] += p * f2.x; acc[5]  += p * f2.y;
    acc[6] += p * f3.x; acc[7]  += p * f3.y;
    acc[8] += p * f4.x; acc[9]  += p * f4.y;
    acc[10] += p * f5.x; acc[11] += p * f5.y;
}

__global__ __launch_bounds__(256) void gat_aggregate_kernel(
    const uint4* __restrict__ Hrec,
    const int* __restrict__ rowptr, const unsigned short* __restrict__ srclist,
    const float* __restrict__ bias,
    _Float16* __restrict__ outYh, int relu)
{
    int s    = blockIdx.x & 7;
    int g    = s >> 1;
    int half = s & 1;
    int local = (blockIdx.x >> 3) * AGG_NPB + (threadIdx.x >> 3);
    if (local >= HALFN) return;
    int n   = half * HALFN + local;
    int l   = threadIdx.x & 7;
    int hh2 = l & 1;
    int j   = l >> 1;

    const uint4* gtab = Hrec + (size_t)g * N_NODES * 4;
    float ad = __uint_as_float(gtab[(size_t)n * 4 + hh2 * 2 + 1].w);

    int s0 = rowptr[n], s1 = rowptr[n + 1];
    float z = 0.f;
    float acc[12];
#pragma unroll
    for (int t = 0; t < 12; t++) acc[t] = 0.f;

    int i = s0 + j;
    for (; i + 12 < s1; i += 16) {
        int sa = srclist[i];
        int sb = srclist[i + 4];
        int sc = srclist[i + 8];
        int sd = srclist[i + 12];
        agg_rec(gtab + (size_t)sa * 4 + hh2 * 2, ad, z, acc);
        agg_rec(gtab + (size_t)sb * 4 + hh2 * 2, ad, z, acc);
        agg_rec(gtab + (size_t)sc * 4 + hh2 * 2, ad, z, acc);
        agg_rec(gtab + (size_t)sd * 4 + hh2 * 2, ad, z, acc);
    }
    for (; i < s1; i += 4) {
        int sa = srclist[i];
        agg_rec(gtab + (size_t)sa * 4 + hh2 * 2, ad, z, acc);
    }

#pragma unroll
    for (int m = 2; m <= 4; m <<= 1) {
        z += __shfl_xor(z, m, 64);
#pragma unroll
        for (int t = 0; t < 12; t++) acc[t] += __shfl_xor(acc[t], m, 64);
    }

    if (j == 0) {
        float inv = 1.f / (z + 1e-16f);
        const float* bp = bias + g * 24 + hh2 * 12;
        float o[12];
#pragma unroll
        for (int t = 0; t < 12; t++) o[t] = acc[t] * inv + bp[t];
        if (relu) {
#pragma unroll
            for (int t = 0; t < 12; t++) o[t] = fmaxf(o[t], 0.f);
        }
        uint ww[6];
#pragma unroll
        for (int t = 0; t < 6; t++) {
            __half2 hv = __floats2half2_rn(o[2 * t], o[2 * t + 1]);
            ww[t] = *(const uint*)&hv;
        }
        uint2* yp = (uint2*)(outYh + (size_t)n * D_HID + g * 24 + hh2 * 12);
        yp[0] = make_uint2(ww[0], ww[1]);
        yp[1] = make_uint2(ww[2], ww[3]);
        yp[2] = make_uint2(ww[4], ww[5]);
    }
}

// ---------------- final linear (96->40) + bias + log_softmax, thread per node --------
// reads fp16 y (halved input traffic vs fp32)
__global__ __launch_bounds__(256) void out_lsm_kernel(
    const _Float16* __restrict__ X, const float* __restrict__ Wout,
    const float* __restrict__ bout, float* __restrict__ out)
{
    __shared__ float Ws[D_HID * N_CLS];
    __shared__ float bs[N_CLS];
    for (int i = threadIdx.x; i < D_HID * N_CLS; i += 256) Ws[i] = Wout[i];
    for (int i = threadIdx.x; i < N_CLS; i += 256) bs[i] = bout[i];
    __syncthreads();

    int n = blockIdx.x * blockDim.x + threadIdx.x;
    if (n >= N_NODES) return;

    float acc[N_CLS];
#pragma unroll
    for (int c = 0; c < N_CLS; c++) acc[c] = bs[c];

    const __half2* xp = (const __half2*)(X + (size_t)n * D_HID);
    for (int k4 = 0; k4 < D_HID / 4; k4++) {
        float2 xa = __half22float2(xp[2 * k4]);
        float2 xb = __half22float2(xp[2 * k4 + 1]);
        const float* wrow = &Ws[(k4 * 4) * N_CLS];
#pragma unroll
        for (int c4 = 0; c4 < N_CLS / 4; c4++) {
            float4 wa = *(const float4*)(wrow + c4 * 4);
            float4 wb = *(const float4*)(wrow + N_CLS + c4 * 4);
            float4 wc = *(const float4*)(wrow + 2 * N_CLS + c4 * 4);
            float4 wd = *(const float4*)(wrow + 3 * N_CLS + c4 * 4);
            acc[c4 * 4 + 0] += xa.x * wa.x + xa.y * wb.x + xb.x * wc.x + xb.y * wd.x;
            acc[c4 * 4 + 1] += xa.x * wa.y + xa.y * wb.y + xb.x * wc.y + xb.y * wd.y;
            acc[c4 * 4 + 2] += xa.x * wa.z + xa.y * wb.z + xb.x * wc.z + xb.y * wd.z;
            acc[c4 * 4 + 3] += xa.x * wa.w + xa.y * wb.w + xb.x * wc.w + xb.y * wd.w;
        }
    }

    float m = acc[0];
#pragma unroll
    for (int c = 1; c < N_CLS; c++) m = fmaxf(m, acc[c]);
    float s = 0.f;
#pragma unroll
    for (int c = 0; c < N_CLS; c++) s += __expf(acc[c] - m);
    float lg = __logf(s);

    float4* op = (float4*)(out + (size_t)n * N_CLS);
#pragma unroll
    for (int c4 = 0; c4 < N_CLS / 4; c4++) {
        op[c4] = make_float4(acc[c4 * 4 + 0] - m - lg, acc[c4 * 4 + 1] - m - lg,
                             acc[c4 * 4 + 2] - m - lg, acc[c4 * 4 + 3] - m - lg);
    }
}

extern "C" void kernel_launch(void* const* d_in, const int* in_sizes, int n_in,
                              void* d_out, int out_size, void* d_ws, size_t ws_size,
                              hipStream_t stream)
{
    const float* x    = (const float*)d_in[0];
    const int*   esrc = (const int*)d_in[1];
    const int*   edst = (const int*)d_in[2];
    const float* W0   = (const float*)d_in[3];
    const float* as0  = (const float*)d_in[4];
    const float* ad0  = (const float*)d_in[5];
    const float* b0   = (const float*)d_in[6];
    const float* W1   = (const float*)d_in[7];
    const float* as1  = (const float*)d_in[8];
    const float* ad1  = (const float*)d_in[9];
    const float* b1   = (const float*)d_in[10];
    const float* Wout = (const float*)d_in[11];
    const float* bout = (const float*)d_in[12];
    float* out = (float*)d_out;

    char* p = (char*)d_ws;
    float*    bufY  = (float*)p;    p += (size_t)N_NODES * D_HID * sizeof(float);
    _Float16* bufYh = (_Float16*)p; p += (size_t)N_NODES * D_HID * sizeof(_Float16);
    uint4*    Hrec  = (uint4*)p;    p += (size_t)4 * N_NODES * 64;   // 4 groups x 64B records
    int*   rowptr = (int*)p;   p += ((size_t)N_NODES + 16) * sizeof(int);
    int*   incl   = (int*)p;   p += ((size_t)N_NODES + 16) * sizeof(int);
    unsigned short* srclist = (unsigned short*)p; p += (size_t)N_EDGES * sizeof(unsigned short);
    int*   partials = (int*)p; p += 256;

    // aliases with disjoint lifetimes (CSR build phase vs layer outputs):
    // Hmat  [CKS][N_NODES] uint16 (6.4MB) in bufYh (9.6MB): dead before agg0 writes bufYh.
    // Bmat16[CKS][N_NODES] uint16 (6.4MB) in bufY: bufY is otherwise unused now.
    unsigned short* Hmat   = (unsigned short*)bufYh;
    unsigned short* Bmat16 = (unsigned short*)bufY;

    int nscan = (N_NODES + 1023) / 1024;   // 49

    // 1. chunk-hist (LDS atomics only) + MFMA gemm0 (in-kernel W0 convert, records out)
    hist_gemm_kernel<<<NHB + NGB, 256, 0, stream>>>(
        edst, Hmat, x, W0, as0, ad0, Hrec);
    // 2. per-bin chunk-sum + block scan
    scan1_kernel<<<nscan, 256, 0, stream>>>(Hmat, incl, partials, N_NODES);
    // 3. rowptr + per-(chunk,bin) relative base offsets (uint16)
    scan3_kernel<<<(N_NODES + 255) / 256, 256, 0, stream>>>(
        incl, partials, Hmat, Bmat16, rowptr, N_NODES, nscan);
    // 4. fill CSR (LDS cursor, no global atomics)
    fill_kernel<<<NHB, 256, 0, stream>>>(esrc, edst, rowptr, Bmat16, srclist);
    // 5. layer-0 aggregate (XCD-partitioned record gather) -> fp16 y
    gat_aggregate_kernel<<<8 * NAGGB, 256, 0, stream>>>(
        Hrec, rowptr, srclist, b0, bufYh, 0);
    // 6. layer-1 MFMA gemm (fp16 A, in-kernel W1 convert) -> records
    gemm_alpha_kernel<<<NGB, 256, 0, stream>>>(
        bufYh, W1, as1, ad1, Hrec, N_NODES, D_HID);
    // 7. layer-1 aggregate + relu -> fp16 y (overwrites bufYh; gemm1 already consumed it)
    gat_aggregate_kernel<<<8 * NAGGB, 256, 0, stream>>>(
        Hrec, rowptr, srclist, b1, bufYh, 1);
    // 8. output linear + log_softmax (fp16 y in)
    out_lsm_kernel<<<(N_NODES + 255) / 256, 256, 0, stream>>>(bufYh, Wout, bout, out);
}